// Round 14
// baseline (4791.608 us; speedup 1.0000x reference)
//
#include <hip/hip_runtime.h>

// LSTM forward, B=32 T=1024 D=512 U=512, fp32.
// Persistent fused kernel, 256 WGs x 512 thr (all co-resident, grid == #CUs).
// Group g = blockIdx&7 (batches 4g..4g+3); WG w = blockIdx>>3 owns units
// [16w,16w+16). Weights in VGPRs as f32x2 col-pairs. Base = R13 (= R9 tied
// best, 4.27ms, with asm sc0 sc1 poll proven neutral/safe).
//
// R14 = R13 + two unbundled shaves:
//  1. poll as 2x global_load_dwordx4 per lane (same bytes, 4x fewer TCC
//     requests). Lane l polls batch l>>4, units 128wv+8(l&15)..+8 (32B
//     contiguous); stages via two ds_write_b128.
//  2. parallel tail (R12's tail, minus its harmful double-poll): all 64
//     lanes gate-path (1 RING read + 8 LR reads), shfl_xor(16/32) gate
//     gather, 4x-redundant c_state, gsel==0 lanes store h; cCRITdone
//     signaled immediately after the RING read.

#define TT 1024
#define DD 512
#define UU 512
#define NCOL 2048
#define SENT 0xFFFFFFFFu
#define RDEPTH 4

typedef float f32x2 __attribute__((ext_vector_type(2)));
typedef float f32x4 __attribute__((ext_vector_type(4)));
typedef unsigned int u32x4 __attribute__((ext_vector_type(4)));

__device__ __forceinline__ float hsig(float v) {
  return fminf(fmaxf(0.2f * v + 0.5f, 0.0f), 1.0f);
}
__device__ __forceinline__ float tanh_fast(float x) {
  float e = __expf(2.0f * x);
  return 1.0f - 2.0f / (e + 1.0f);
}

// Epoch barrier for the 4 waves of one half (waves 0-3 or 4-7).
template <bool SLEEP>
__device__ __forceinline__ void wavebar(int* ctr, int& ep) {
  asm volatile("s_waitcnt lgkmcnt(0)" ::: "memory");
  if ((threadIdx.x & 63) == 0)
    __hip_atomic_fetch_add(ctr, 1, __ATOMIC_RELAXED, __HIP_MEMORY_SCOPE_WORKGROUP);
  ep += 4;
  while (__hip_atomic_load(ctr, __ATOMIC_RELAXED, __HIP_MEMORY_SCOPE_WORKGROUP) < ep) {
    if (SLEEP) __builtin_amdgcn_s_sleep(1);
  }
  asm volatile("" ::: "memory");
}

__global__ __launch_bounds__(512, 2) void lstm_persistent(
    const float* __restrict__ x,
    const float* __restrict__ Wk,
    const float* __restrict__ Wr,
    const float* __restrict__ bias,
    float* __restrict__ out) {
  const int tid = (int)threadIdx.x;
  const int g   = (int)blockIdx.x & 7;
  const int w   = (int)blockIdx.x >> 3;
  const bool crit = (tid < 256);
  const int l   = tid & 63;

  __shared__ float LX[8][4][65];
  __shared__ float LR[2][8][4][66];
  __shared__ float RING[RDEPTH][4][66];
  __shared__ float LH[4][8][68];
  __shared__ float LB[64];
  __shared__ int cXZdone, cCRITdone, cXZbar, cCRITbar;

  if (tid == 0) { cXZdone = 0; cCRITdone = 0; cXZbar = 0; cCRITbar = 0; }
  if (tid < 64) LB[tid] = bias[(tid >> 4) * UU + w * 16 + (tid & 15)];

  f32x2 W2[64];
  {
    const int wv  = tid >> 6;
    const int idx = tid & 255;
    const int cp  = crit ? (l & 31) : (idx & 31);
    const int ko  = crit ? (2 * (wv & 3) + (l >> 5)) : (idx >> 5);
    const int gcb = (cp >> 3) * UU + w * 16 + ((2 * cp) & 15);
    const float* M = crit ? Wr : Wk;
#pragma unroll
    for (int j = 0; j < 64; ++j)
      W2[j] = *(const f32x2*)(M + (size_t)(64 * ko + j) * NCOL + gcb);
  }
  __syncthreads();  // one-time init barrier only

  if (crit) {
    // ---------------- critical path: waves 0-3 ----------------
    const int wv   = tid >> 6;       // wave id; poll-slice + LR octants
    const int kq0  = 2 * wv;
    const int kql  = kq0 + (l >> 5);
    const int cp   = l & 31;
    const int gsel = l >> 4;         // gate of this lane for the tail
    // Poll mapping: lane covers batch b_p, units 128wv + 8m .. +8 (32B).
    const int b_p  = l >> 4;
    const int m    = l & 15;
    const unsigned* hb = (const unsigned*)out +
        (size_t)(g * 4 + b_p) * TT * UU + 128 * wv + 8 * m;
    float* lhdst = &LH[b_p][kq0 + (m >> 3)][8 * (m & 7)];
    float c_state = 0.0f;            // copy for (batch wv, unit l&15)
    int epC = 0;

    for (int t = 0; t < TT; ++t) {
      if (t > 0) {
        // ---- slice-local data-poll: 2x dwordx4, 1 RTT, sc0 sc1 ----
        const unsigned* p = hb + (size_t)(t - 1) * UU;
        u32x4 A, B;
        for (;;) {
          asm volatile(
              "global_load_dwordx4 %0, %2, off sc0 sc1\n\t"
              "global_load_dwordx4 %1, %2, off offset:16 sc0 sc1\n\t"
              "s_waitcnt vmcnt(0)"
              : "=v"(A), "=v"(B) : "v"(p) : "memory");
          int ok = (A.x != SENT) & (A.y != SENT) & (A.z != SENT) & (A.w != SENT) &
                   (B.x != SENT) & (B.y != SENT) & (B.z != SENT) & (B.w != SENT);
          if (__all(ok)) break;
          __builtin_amdgcn_s_sleep(1);
        }
        // ---- stage into this wave's LH octants: two ds_write_b128 ----
        *(u32x4*)lhdst       = A;
        *(u32x4*)(lhdst + 4) = B;
        asm volatile("s_waitcnt lgkmcnt(0)" ::: "memory");
        __builtin_amdgcn_sched_barrier(0);
        // ---- dot: 2 cols x 64 k x 4 batches, f32x2 acc (v_pk_fma) ----
        __builtin_amdgcn_s_setprio(1);
        f32x2 a0 = {0.f, 0.f}, a1 = {0.f, 0.f}, a2 = {0.f, 0.f}, a3 = {0.f, 0.f};
#pragma unroll
        for (int j4 = 0; j4 < 16; ++j4) {
          f32x4 h0 = *(const f32x4*)&LH[0][kql][4 * j4];
          f32x4 h1 = *(const f32x4*)&LH[1][kql][4 * j4];
          f32x4 h2 = *(const f32x4*)&LH[2][kql][4 * j4];
          f32x4 h3 = *(const f32x4*)&LH[3][kql][4 * j4];
#pragma unroll
          for (int jj = 0; jj < 4; ++jj) {
            f32x2 wj = W2[4 * j4 + jj];
            a0 += (f32x2){h0[jj], h0[jj]} * wj;
            a1 += (f32x2){h1[jj], h1[jj]} * wj;
            a2 += (f32x2){h2[jj], h2[jj]} * wj;
            a3 += (f32x2){h3[jj], h3[jj]} * wj;
          }
        }
        __builtin_amdgcn_s_setprio(0);
        const int p2 = t & 1;
        *(f32x2*)&LR[p2][kql][0][2 * cp] = a0;
        *(f32x2*)&LR[p2][kql][1][2 * cp] = a1;
        *(f32x2*)&LR[p2][kql][2][2 * cp] = a2;
        *(f32x2*)&LR[p2][kql][3][2 * cp] = a3;
      }
      // ---- pre-gate: xz + bias, ONE LDS read per lane (col l) ----
      while (__hip_atomic_load(&cXZdone, __ATOMIC_RELAXED,
                               __HIP_MEMORY_SCOPE_WORKGROUP) < t + 1) {
      }
      asm volatile("" ::: "memory");
      float s = RING[t & (RDEPTH - 1)][wv][l] + LB[l];
      if (l == 0)
        __hip_atomic_fetch_add(&cCRITdone, 1, __ATOMIC_RELAXED,
                               __HIP_MEMORY_SCOPE_WORKGROUP);
      wavebar<false>(&cCRITbar, epC);  // B2: all LR partials complete
      if (t > 0) {
        const int p2 = t & 1;
#pragma unroll
        for (int kq = 0; kq < 8; ++kq) s += LR[p2][kq][wv][l];
      }
      // ---- gate gather: gate q of unit u lives in lane 16q+u ----
      float za  = __shfl_xor(s, 16);   // gate gsel^1
      float zb  = __shfl_xor(s, 32);   // gate gsel^2
      float zc2 = __shfl_xor(za, 32);  // gate gsel^3
      float zi  = gsel == 0 ? s   : gsel == 1 ? za  : gsel == 2 ? zb  : zc2;
      float zf  = gsel == 0 ? za  : gsel == 1 ? s   : gsel == 2 ? zc2 : zb;
      float zc_ = gsel == 0 ? zb  : gsel == 1 ? zc2 : gsel == 2 ? s   : za;
      float zo  = gsel == 0 ? zc2 : gsel == 1 ? zb  : gsel == 2 ? za  : s;
      float gi = hsig(zi);
      float gf = hsig(zf);
      float gc = tanh_fast(zc_);
      float go = hsig(zo);
      c_state = gf * c_state + gi * gc;  // 4 redundant identical copies/unit
      float h = go * tanh_fast(c_state);
      if (gsel == 0) {  // 16 lanes store: (batch wv, unit w*16 + l)
        __hip_atomic_store(
            out + ((size_t)(g * 4 + wv) * TT + t) * UU + w * 16 + l, h,
            __ATOMIC_RELAXED, __HIP_MEMORY_SCOPE_AGENT);
      }
    }
  } else {
    // ---------------- xz pipeline: waves 4-7 (free-running) ----------------
    const int idx = tid & 255;
    const int o   = idx >> 5;
    const int cp  = idx & 31;
    const float* xb0 = x + (size_t)(g * 4 + 0) * TT * DD + o * 64;
    const float* xb1 = x + (size_t)(g * 4 + 1) * TT * DD + o * 64;
    const float* xb2 = x + (size_t)(g * 4 + 2) * TT * DD + o * 64;
    const float* xb3 = x + (size_t)(g * 4 + 3) * TT * DD + o * 64;
    int epX = 0;

    for (int t = 0; t < TT; ++t) {
      const size_t off = (size_t)t * DD;
      f32x2 a0 = {0.f, 0.f}, a1 = {0.f, 0.f}, a2 = {0.f, 0.f}, a3 = {0.f, 0.f};
#pragma unroll
      for (int j4 = 0; j4 < 16; ++j4) {
        f32x4 v0 = *(const f32x4*)(xb0 + off + 4 * j4);
        f32x4 v1 = *(const f32x4*)(xb1 + off + 4 * j4);
        f32x4 v2 = *(const f32x4*)(xb2 + off + 4 * j4);
        f32x4 v3 = *(const f32x4*)(xb3 + off + 4 * j4);
#pragma unroll
        for (int jj = 0; jj < 4; ++jj) {
          f32x2 wj = W2[4 * j4 + jj];
          a0 += (f32x2){v0[jj], v0[jj]} * wj;
          a1 += (f32x2){v1[jj], v1[jj]} * wj;
          a2 += (f32x2){v2[jj], v2[jj]} * wj;
          a3 += (f32x2){v3[jj], v3[jj]} * wj;
        }
      }
      *(f32x2*)&LX[o][0][2 * cp] = a0;
      *(f32x2*)&LX[o][1][2 * cp] = a1;
      *(f32x2*)&LX[o][2][2 * cp] = a2;
      *(f32x2*)&LX[o][3][2 * cp] = a3;
      wavebar<true>(&cXZbar, epX);  // partials visible
      if (t >= RDEPTH) {
        while (__hip_atomic_load(&cCRITdone, __ATOMIC_RELAXED,
                                 __HIP_MEMORY_SCOPE_WORKGROUP) <
               4 * (t - RDEPTH + 1)) {
          __builtin_amdgcn_s_sleep(1);
        }
        asm volatile("" ::: "memory");
      }
      {
        const int b2 = idx >> 6, c3 = idx & 63;
        float ssum = 0.f;
#pragma unroll
        for (int oo = 0; oo < 8; ++oo) ssum += LX[oo][b2][c3];
        RING[t & (RDEPTH - 1)][b2][c3] = ssum;
      }
      wavebar<true>(&cXZbar, epX);  // reduce complete (guards LX overwrite)
      if (idx == 0) {
        asm volatile("s_waitcnt lgkmcnt(0)" ::: "memory");
        __hip_atomic_fetch_add(&cXZdone, 1, __ATOMIC_RELAXED,
                               __HIP_MEMORY_SCOPE_WORKGROUP);
      }
    }
  }
}

extern "C" void kernel_launch(void* const* d_in, const int* in_sizes, int n_in,
                              void* d_out, int out_size, void* d_ws, size_t ws_size,
                              hipStream_t stream) {
  const float* x    = (const float*)d_in[0];
  const float* Wk   = (const float*)d_in[1];
  const float* Wr   = (const float*)d_in[2];
  const float* bias = (const float*)d_in[3];
  float* out = (float*)d_out;

  // Sentinel-fill the h history (graph-capturable async memset).
  hipMemsetAsync(out, 0xFF, (size_t)out_size * sizeof(float), stream);
  lstm_persistent<<<256, 512, 0, stream>>>(x, Wk, Wr, bias, out);
}

// Round 15
// 4607.037 us; speedup vs baseline: 1.0401x; 1.0401x over previous
//
#include <hip/hip_runtime.h>

// LSTM forward, B=32 T=1024 D=512 U=512, fp32.
// Persistent fused kernel, 256 WGs x 512 thr (all co-resident, grid == #CUs).
// Group g = blockIdx&7 (batches 4g..4g+3); WG w = blockIdx>>3 owns units
// [16w,16w+16). Weights in VGPRs as f32x2 col-pairs.
//
// R15: TWO INDEPENDENT 2-BATCH CHAINS per group (A = batches 0-1, B = 2-3),
// software-pipelined so each chain's store->visibility->detect latency
// elapses under the OTHER chain's compute. Key mechanism (fixes R10):
// speculative sentinel loads are ISSUED EARLY (no wait) and checked later
// with counted s_waitcnt vmcnt(4) (leaves the other chain's 4 loads in
// flight). Failed check -> proven R13 re-poll loop (sc0 sc1). No replica
// redundancy: same producers, same total FLOP/stores as R9.
// Per iteration (all crit waves):
//   [0] issue specB(h_B(t-1))   [1] check A (vmcnt4) / repoll, stage, dot_A
//   [3] tailA: RING_A wait, B2a, gates_A (waves 0-1, 16-lane), store h_A(t)
//   [4] issue specA(h_A(t))     [5] check B (vmcnt4) / repoll, stage, dot_B
//   [7] tailB: RING_B wait, B2b, gates_B (waves 2-3), store h_B(t)
// 16-lane serial tail kept (R12/R14: shfl tail costs +0.5us).

#define TT 1024
#define DD 512
#define UU 512
#define NCOL 2048
#define SENT 0xFFFFFFFFu
#define RDEPTH 4

typedef float f32x2 __attribute__((ext_vector_type(2)));
typedef float f32x4 __attribute__((ext_vector_type(4)));

__device__ __forceinline__ float hsig(float v) {
  return fminf(fmaxf(0.2f * v + 0.5f, 0.0f), 1.0f);
}
__device__ __forceinline__ float tanh_fast(float x) {
  float e = __expf(2.0f * x);
  return 1.0f - 2.0f / (e + 1.0f);
}

template <bool SLEEP>
__device__ __forceinline__ void wavebar(int* ctr, int& ep) {
  asm volatile("s_waitcnt lgkmcnt(0)" ::: "memory");
  if ((threadIdx.x & 63) == 0)
    __hip_atomic_fetch_add(ctr, 1, __ATOMIC_RELAXED, __HIP_MEMORY_SCOPE_WORKGROUP);
  ep += 4;
  while (__hip_atomic_load(ctr, __ATOMIC_RELAXED, __HIP_MEMORY_SCOPE_WORKGROUP) < ep) {
    if (SLEEP) __builtin_amdgcn_s_sleep(1);
  }
  asm volatile("" ::: "memory");
}

// Issue 4 sentinel loads, no wait (speculative).
#define ISSUE4(v0, v1, v2, v3, p0, p1)                                   \
  asm volatile(                                                          \
      "global_load_dword %0, %4, off sc0 sc1\n\t"                        \
      "global_load_dword %1, %4, off offset:256 sc0 sc1\n\t"             \
      "global_load_dword %2, %5, off sc0 sc1\n\t"                        \
      "global_load_dword %3, %5, off offset:256 sc0 sc1"                 \
      : "=v"(v0), "=v"(v1), "=v"(v2), "=v"(v3)                           \
      : "v"(p0), "v"(p1)                                                 \
      : "memory")

// Counted drain: ties reg liveness across the waitcnt (values final after).
#define DRAIN4(v0, v1, v2, v3)                                           \
  asm volatile("s_waitcnt vmcnt(4)"                                      \
               : "+v"(v0), "+v"(v1), "+v"(v2), "+v"(v3)::"memory")

#define OK4(v0, v1, v2, v3)                                              \
  ((v0 != SENT) & (v1 != SENT) & (v2 != SENT) & (v3 != SENT))

// Fallback re-poll (R13-proven form).
#define REPOLL4(v0, v1, v2, v3, p0, p1)                                  \
  for (;;) {                                                             \
    asm volatile(                                                        \
        "global_load_dword %0, %4, off sc0 sc1\n\t"                      \
        "global_load_dword %1, %4, off offset:256 sc0 sc1\n\t"           \
        "global_load_dword %2, %5, off sc0 sc1\n\t"                      \
        "global_load_dword %3, %5, off offset:256 sc0 sc1\n\t"           \
        "s_waitcnt vmcnt(0)"                                             \
        : "=v"(v0), "=v"(v1), "=v"(v2), "=v"(v3)                         \
        : "v"(p0), "v"(p1)                                               \
        : "memory");                                                     \
    if (__all(OK4(v0, v1, v2, v3))) break;                               \
    __builtin_amdgcn_s_sleep(1);                                         \
  }

__global__ __launch_bounds__(512, 2) void lstm_persistent(
    const float* __restrict__ x,
    const float* __restrict__ Wk,
    const float* __restrict__ Wr,
    const float* __restrict__ bias,
    float* __restrict__ out) {
  const int tid = (int)threadIdx.x;
  const int g   = (int)blockIdx.x & 7;
  const int w   = (int)blockIdx.x >> 3;
  const bool crit = (tid < 256);
  const int l   = tid & 63;

  __shared__ float LX[8][2][66];           // xz partials (per-phase serial)
  __shared__ float LR[2][2][8][2][66];     // [phase][parity][kq][bi][col]
  __shared__ float RING[2][RDEPTH][2][66]; // [phase][slot][bi][col]
  __shared__ float LH[2][2][8][68];        // [phase][bi][kq][unit]
  __shared__ float LB[64];
  __shared__ int cXZdone[2], cCRITdone[2], cXZbar, cCRITbar;

  if (tid < 2) { cXZdone[tid] = 0; cCRITdone[tid] = 0; }
  if (tid == 0) { cXZbar = 0; cCRITbar = 0; }
  if (tid < 64) LB[tid] = bias[(tid >> 4) * UU + w * 16 + (tid & 15)];

  f32x2 W2[64];
  {
    const int wv  = tid >> 6;
    const int idx = tid & 255;
    const int cp  = crit ? (l & 31) : (idx & 31);
    const int ko  = crit ? (2 * (wv & 3) + (l >> 5)) : (idx >> 5);
    const int gcb = (cp >> 3) * UU + w * 16 + ((2 * cp) & 15);
    const float* M = crit ? Wr : Wk;
#pragma unroll
    for (int j = 0; j < 64; ++j)
      W2[j] = *(const f32x2*)(M + (size_t)(64 * ko + j) * NCOL + gcb);
  }
  __syncthreads();  // one-time init barrier only

  if (crit) {
    // ---------------- critical path: waves 0-3, two chains ----------------
    const int wv   = tid >> 6;
    const int kq0  = 2 * wv;
    const int kql  = kq0 + (l >> 5);
    const int cp   = l & 31;
    const int myp  = wv >> 1;    // this wave's gate phase (0=A,1=B)
    const int mybi = wv & 1;     // batch-in-phase for gates
    // oub[phase][bi]: h base of batch g*4 + 2*phase + bi
    const unsigned* oub[2][2];
#pragma unroll
    for (int p = 0; p < 2; ++p)
#pragma unroll
      for (int bi = 0; bi < 2; ++bi)
        oub[p][bi] = (const unsigned*)out + (size_t)(g * 4 + 2 * p + bi) * TT * UU;
    const size_t sl = 128 * wv + l;  // this lane's poll slice offset
    float c_state = 0.0f;
    int epC = 0;
    unsigned sa0, sa1, sa2, sa3, sb0, sb1, sb2, sb3;

    for (int t = 0; t < TT; ++t) {
      // ---- [0] issue specB for h_B(t-1) ----
      if (t > 0) {
        const size_t ro = (size_t)(t - 1) * UU + sl;
        ISSUE4(sb0, sb1, sb2, sb3, oub[1][0] + ro, oub[1][1] + ro);
      }
      // ---- [1] check A (issued at prev [4]); stage + dot_A ----
      if (t > 0) {
        const size_t ro = (size_t)(t - 1) * UU + sl;
        DRAIN4(sa0, sa1, sa2, sa3);
        if (!__all(OK4(sa0, sa1, sa2, sa3))) {
          REPOLL4(sa0, sa1, sa2, sa3, oub[0][0] + ro, oub[0][1] + ro);
        }
        LH[0][0][kq0    ][l] = __uint_as_float(sa0);
        LH[0][0][kq0 + 1][l] = __uint_as_float(sa1);
        LH[0][1][kq0    ][l] = __uint_as_float(sa2);
        LH[0][1][kq0 + 1][l] = __uint_as_float(sa3);
        asm volatile("s_waitcnt lgkmcnt(0)" ::: "memory");
        __builtin_amdgcn_sched_barrier(0);
        __builtin_amdgcn_s_setprio(1);
        f32x2 a0 = {0.f, 0.f}, a1 = {0.f, 0.f};
#pragma unroll
        for (int j4 = 0; j4 < 16; ++j4) {
          f32x4 h0 = *(const f32x4*)&LH[0][0][kql][4 * j4];
          f32x4 h1 = *(const f32x4*)&LH[0][1][kql][4 * j4];
#pragma unroll
          for (int jj = 0; jj < 4; ++jj) {
            f32x2 wj = W2[4 * j4 + jj];
            a0 += (f32x2){h0[jj], h0[jj]} * wj;
            a1 += (f32x2){h1[jj], h1[jj]} * wj;
          }
        }
        __builtin_amdgcn_s_setprio(0);
        *(f32x2*)&LR[0][t & 1][kql][0][2 * cp] = a0;
        *(f32x2*)&LR[0][t & 1][kql][1][2 * cp] = a1;
      }
      // ---- [3] tail A (waves 0-1, 16-lane serial) ----
      float s0 = 0.f, s1 = 0.f, s2 = 0.f, s3 = 0.f;
      if (myp == 0 && l < 16) {
        while (__hip_atomic_load(&cXZdone[0], __ATOMIC_RELAXED,
                                 __HIP_MEMORY_SCOPE_WORKGROUP) < t + 1) {
        }
        asm volatile("" ::: "memory");
        const int ss = t & (RDEPTH - 1);
        s0 = RING[0][ss][mybi][l +  0] + LB[l +  0];
        s1 = RING[0][ss][mybi][l + 16] + LB[l + 16];
        s2 = RING[0][ss][mybi][l + 32] + LB[l + 32];
        s3 = RING[0][ss][mybi][l + 48] + LB[l + 48];
        if (wv == 0 && l == 0) {
          asm volatile("s_waitcnt lgkmcnt(0)" ::: "memory");
          __hip_atomic_fetch_add(&cCRITdone[0], 1, __ATOMIC_RELAXED,
                                 __HIP_MEMORY_SCOPE_WORKGROUP);
        }
      }
      wavebar<false>(&cCRITbar, epC);  // B2a: LR[0] complete
      if (myp == 0 && l < 16) {
        if (t > 0) {
          const int par = t & 1;
#pragma unroll
          for (int kq = 0; kq < 8; ++kq) {
            s0 += LR[0][par][kq][mybi][l +  0];
            s1 += LR[0][par][kq][mybi][l + 16];
            s2 += LR[0][par][kq][mybi][l + 32];
            s3 += LR[0][par][kq][mybi][l + 48];
          }
        }
        float gi = hsig(s0), gf = hsig(s1);
        float gc = tanh_fast(s2), go = hsig(s3);
        c_state = gf * c_state + gi * gc;
        float h = go * tanh_fast(c_state);
        __hip_atomic_store(
            out + ((size_t)(g * 4 + mybi) * TT + t) * UU + w * 16 + l, h,
            __ATOMIC_RELAXED, __HIP_MEMORY_SCOPE_AGENT);
      }
      // ---- [4] issue specA for h_A(t) (next iteration's check) ----
      {
        const size_t ro = (size_t)t * UU + sl;
        ISSUE4(sa0, sa1, sa2, sa3, oub[0][0] + ro, oub[0][1] + ro);
      }
      // ---- [5] check B; stage + dot_B ----
      if (t > 0) {
        const size_t ro = (size_t)(t - 1) * UU + sl;
        DRAIN4(sb0, sb1, sb2, sb3);
        if (!__all(OK4(sb0, sb1, sb2, sb3))) {
          REPOLL4(sb0, sb1, sb2, sb3, oub[1][0] + ro, oub[1][1] + ro);
        }
        LH[1][0][kq0    ][l] = __uint_as_float(sb0);
        LH[1][0][kq0 + 1][l] = __uint_as_float(sb1);
        LH[1][1][kq0    ][l] = __uint_as_float(sb2);
        LH[1][1][kq0 + 1][l] = __uint_as_float(sb3);
        asm volatile("s_waitcnt lgkmcnt(0)" ::: "memory");
        __builtin_amdgcn_sched_barrier(0);
        __builtin_amdgcn_s_setprio(1);
        f32x2 b0 = {0.f, 0.f}, b1 = {0.f, 0.f};
#pragma unroll
        for (int j4 = 0; j4 < 16; ++j4) {
          f32x4 h0 = *(const f32x4*)&LH[1][0][kql][4 * j4];
          f32x4 h1 = *(const f32x4*)&LH[1][1][kql][4 * j4];
#pragma unroll
          for (int jj = 0; jj < 4; ++jj) {
            f32x2 wj = W2[4 * j4 + jj];
            b0 += (f32x2){h0[jj], h0[jj]} * wj;
            b1 += (f32x2){h1[jj], h1[jj]} * wj;
          }
        }
        __builtin_amdgcn_s_setprio(0);
        *(f32x2*)&LR[1][t & 1][kql][0][2 * cp] = b0;
        *(f32x2*)&LR[1][t & 1][kql][1][2 * cp] = b1;
      }
      // ---- [7] tail B (waves 2-3) ----
      s0 = 0.f; s1 = 0.f; s2 = 0.f; s3 = 0.f;
      if (myp == 1 && l < 16) {
        while (__hip_atomic_load(&cXZdone[1], __ATOMIC_RELAXED,
                                 __HIP_MEMORY_SCOPE_WORKGROUP) < t + 1) {
        }
        asm volatile("" ::: "memory");
        const int ss = t & (RDEPTH - 1);
        s0 = RING[1][ss][mybi][l +  0] + LB[l +  0];
        s1 = RING[1][ss][mybi][l + 16] + LB[l + 16];
        s2 = RING[1][ss][mybi][l + 32] + LB[l + 32];
        s3 = RING[1][ss][mybi][l + 48] + LB[l + 48];
        if (wv == 2 && l == 0) {
          asm volatile("s_waitcnt lgkmcnt(0)" ::: "memory");
          __hip_atomic_fetch_add(&cCRITdone[1], 1, __ATOMIC_RELAXED,
                                 __HIP_MEMORY_SCOPE_WORKGROUP);
        }
      }
      wavebar<false>(&cCRITbar, epC);  // B2b: LR[1] complete
      if (myp == 1 && l < 16) {
        if (t > 0) {
          const int par = t & 1;
#pragma unroll
          for (int kq = 0; kq < 8; ++kq) {
            s0 += LR[1][par][kq][mybi][l +  0];
            s1 += LR[1][par][kq][mybi][l + 16];
            s2 += LR[1][par][kq][mybi][l + 32];
            s3 += LR[1][par][kq][mybi][l + 48];
          }
        }
        float gi = hsig(s0), gf = hsig(s1);
        float gc = tanh_fast(s2), go = hsig(s3);
        c_state = gf * c_state + gi * gc;
        float h = go * tanh_fast(c_state);
        __hip_atomic_store(
            out + ((size_t)(g * 4 + 2 + mybi) * TT + t) * UU + w * 16 + l, h,
            __ATOMIC_RELAXED, __HIP_MEMORY_SCOPE_AGENT);
      }
    }
    asm volatile("s_waitcnt vmcnt(0) lgkmcnt(0)" ::: "memory");  // drain specs
  } else {
    // ---------------- xz pipeline: waves 4-7, two phases per t ------------
    const int idx = tid & 255;
    const int o   = idx >> 5;
    const int cp  = idx & 31;
    const float* xb[2][2];
#pragma unroll
    for (int p = 0; p < 2; ++p)
#pragma unroll
      for (int bi = 0; bi < 2; ++bi)
        xb[p][bi] = x + (size_t)(g * 4 + 2 * p + bi) * TT * DD + o * 64;
    int epX = 0;

    for (int t = 0; t < TT; ++t) {
#pragma unroll
      for (int p = 0; p < 2; ++p) {
        const size_t off = (size_t)t * DD;
        f32x2 a0 = {0.f, 0.f}, a1 = {0.f, 0.f};
#pragma unroll
        for (int j4 = 0; j4 < 16; ++j4) {
          f32x4 v0 = *(const f32x4*)(xb[p][0] + off + 4 * j4);
          f32x4 v1 = *(const f32x4*)(xb[p][1] + off + 4 * j4);
#pragma unroll
          for (int jj = 0; jj < 4; ++jj) {
            f32x2 wj = W2[4 * j4 + jj];
            a0 += (f32x2){v0[jj], v0[jj]} * wj;
            a1 += (f32x2){v1[jj], v1[jj]} * wj;
          }
        }
        *(f32x2*)&LX[o][0][2 * cp] = a0;
        *(f32x2*)&LX[o][1][2 * cp] = a1;
        wavebar<true>(&cXZbar, epX);  // partials visible
        if (t >= RDEPTH) {
          while (__hip_atomic_load(&cCRITdone[p], __ATOMIC_RELAXED,
                                   __HIP_MEMORY_SCOPE_WORKGROUP) <
                 t - RDEPTH + 1) {
            __builtin_amdgcn_s_sleep(1);
          }
          asm volatile("" ::: "memory");
        }
        if (idx < 128) {
          const int bi = idx >> 6, c3 = idx & 63;
          float ssum = 0.f;
#pragma unroll
          for (int oo = 0; oo < 8; ++oo) ssum += LX[oo][bi][c3];
          RING[p][t & (RDEPTH - 1)][bi][c3] = ssum;
        }
        wavebar<true>(&cXZbar, epX);  // reduce complete (guards LX overwrite)
        if (idx == 0) {
          asm volatile("s_waitcnt lgkmcnt(0)" ::: "memory");
          __hip_atomic_fetch_add(&cXZdone[p], 1, __ATOMIC_RELAXED,
                                 __HIP_MEMORY_SCOPE_WORKGROUP);
        }
      }
    }
  }
}

extern "C" void kernel_launch(void* const* d_in, const int* in_sizes, int n_in,
                              void* d_out, int out_size, void* d_ws, size_t ws_size,
                              hipStream_t stream) {
  const float* x    = (const float*)d_in[0];
  const float* Wk   = (const float*)d_in[1];
  const float* Wr   = (const float*)d_in[2];
  const float* bias = (const float*)d_in[3];
  float* out = (float*)d_out;

  // Sentinel-fill the h history (graph-capturable async memset).
  hipMemsetAsync(out, 0xFF, (size_t)out_size * sizeof(float), stream);
  lstm_persistent<<<256, 512, 0, stream>>>(x, Wk, Wr, bias, out);
}

// Round 16
// 4258.134 us; speedup vs baseline: 1.1253x; 1.0819x over previous
//
#include <hip/hip_runtime.h>

// LSTM forward, B=32 T=1024 D=512 U=512, fp32.
// Persistent fused kernel, 256 WGs x 512 thr (all co-resident, grid == #CUs).
// Group g = blockIdx&7 (batches 4g..4g+3); WG w = blockIdx>>3 owns units
// [16w,16w+16). Weights in VGPRs as f32x2 col-pairs.
//
// R16 = EXACT R13 (tied best, 4.27ms) with ONE variable changed:
// crit-poll backoff s_sleep(1) -> s_sleep(16) (~0.43us idle per failed
// iteration, ~2x fewer poll shots at the LLC).
// Hypothesis under test: producers' h stores queue behind the ~1024
// polling waves' near-continuous sc0/sc1 read traffic at the coherent
// point (R8: 4x poll traffic -> 2.3x slower; R12: 2x -> 1.13x slower).
// Throttling the poll frees LLC queue slots -> stores land earlier ->
// the ~3us "visibility" term shrinks. Detection quantization cost is
// bounded (~+0.2us). If neutral/worse: the exchange term is a hard
// latency floor and the structure is at its ceiling.

#define TT 1024
#define DD 512
#define UU 512
#define NCOL 2048
#define SENT 0xFFFFFFFFu
#define RDEPTH 4

typedef float f32x2 __attribute__((ext_vector_type(2)));
typedef float f32x4 __attribute__((ext_vector_type(4)));

__device__ __forceinline__ float hsig(float v) {
  return fminf(fmaxf(0.2f * v + 0.5f, 0.0f), 1.0f);
}
__device__ __forceinline__ float tanh_fast(float x) {
  float e = __expf(2.0f * x);
  return 1.0f - 2.0f / (e + 1.0f);
}

// Epoch barrier for the 4 waves of one half (waves 0-3 or 4-7).
template <bool SLEEP>
__device__ __forceinline__ void wavebar(int* ctr, int& ep) {
  asm volatile("s_waitcnt lgkmcnt(0)" ::: "memory");
  if ((threadIdx.x & 63) == 0)
    __hip_atomic_fetch_add(ctr, 1, __ATOMIC_RELAXED, __HIP_MEMORY_SCOPE_WORKGROUP);
  ep += 4;
  while (__hip_atomic_load(ctr, __ATOMIC_RELAXED, __HIP_MEMORY_SCOPE_WORKGROUP) < ep) {
    if (SLEEP) __builtin_amdgcn_s_sleep(1);
  }
  asm volatile("" ::: "memory");
}

__global__ __launch_bounds__(512, 2) void lstm_persistent(
    const float* __restrict__ x,
    const float* __restrict__ Wk,
    const float* __restrict__ Wr,
    const float* __restrict__ bias,
    float* __restrict__ out) {
  const int tid = (int)threadIdx.x;
  const int g   = (int)blockIdx.x & 7;
  const int w   = (int)blockIdx.x >> 3;
  const bool crit = (tid < 256);
  const int l   = tid & 63;

  __shared__ float LX[8][4][65];
  __shared__ float LR[2][8][4][66];
  __shared__ float RING[RDEPTH][4][66];
  __shared__ float LH[4][8][68];
  __shared__ float LB[64];
  __shared__ int cXZdone, cCRITdone, cXZbar, cCRITbar;

  if (tid == 0) { cXZdone = 0; cCRITdone = 0; cXZbar = 0; cCRITbar = 0; }
  if (tid < 64) LB[tid] = bias[(tid >> 4) * UU + w * 16 + (tid & 15)];

  f32x2 W2[64];
  {
    const int wv  = tid >> 6;
    const int idx = tid & 255;
    const int cp  = crit ? (l & 31) : (idx & 31);
    const int ko  = crit ? (2 * (wv & 3) + (l >> 5)) : (idx >> 5);
    const int gcb = (cp >> 3) * UU + w * 16 + ((2 * cp) & 15);
    const float* M = crit ? Wr : Wk;
#pragma unroll
    for (int j = 0; j < 64; ++j)
      W2[j] = *(const f32x2*)(M + (size_t)(64 * ko + j) * NCOL + gcb);
  }
  __syncthreads();  // one-time init barrier only

  if (crit) {
    // ---------------- critical path: waves 0-3 ----------------
    const int wv  = tid >> 6;        // wave id; poll-slice + batch wv
    const int kq0 = 2 * wv;
    const int kql = kq0 + (l >> 5);
    const int cp  = l & 31;
    const unsigned* ou0 = (const unsigned*)out + (size_t)(g * 4 + 0) * TT * UU;
    const unsigned* ou1 = (const unsigned*)out + (size_t)(g * 4 + 1) * TT * UU;
    const unsigned* ou2 = (const unsigned*)out + (size_t)(g * 4 + 2) * TT * UU;
    const unsigned* ou3 = (const unsigned*)out + (size_t)(g * 4 + 3) * TT * UU;
    float c_state = 0.0f;            // lanes 0-15: c for (batch wv, unit l)
    int epC = 0;

    for (int t = 0; t < TT; ++t) {
      if (t > 0) {
        // ---- slice-local data-poll: 8 words, 1 RTT, 8 producer WGs ----
        // asm sc0 sc1: bypass L1, read the LLC coherence point every iter.
        // Backoff s_sleep(16): throttle poll pressure on the LLC.
        const size_t roff = (size_t)(t - 1) * UU + 128 * wv + l;
        const unsigned* p0 = ou0 + roff;
        const unsigned* p1 = ou1 + roff;
        const unsigned* p2 = ou2 + roff;
        const unsigned* p3 = ou3 + roff;
        unsigned v0, v1, v2, v3, v4, v5, v6, v7;
        for (;;) {
          asm volatile(
              "global_load_dword %0, %8, off sc0 sc1\n\t"
              "global_load_dword %1, %8, off offset:256 sc0 sc1\n\t"
              "global_load_dword %2, %9, off sc0 sc1\n\t"
              "global_load_dword %3, %9, off offset:256 sc0 sc1\n\t"
              "global_load_dword %4, %10, off sc0 sc1\n\t"
              "global_load_dword %5, %10, off offset:256 sc0 sc1\n\t"
              "global_load_dword %6, %11, off sc0 sc1\n\t"
              "global_load_dword %7, %11, off offset:256 sc0 sc1\n\t"
              "s_waitcnt vmcnt(0)"
              : "=v"(v0), "=v"(v1), "=v"(v2), "=v"(v3),
                "=v"(v4), "=v"(v5), "=v"(v6), "=v"(v7)
              : "v"(p0), "v"(p1), "v"(p2), "v"(p3)
              : "memory");
          int ok = (v0 != SENT) & (v1 != SENT) & (v2 != SENT) & (v3 != SENT) &
                   (v4 != SENT) & (v5 != SENT) & (v6 != SENT) & (v7 != SENT);
          if (__all(ok)) break;
          __builtin_amdgcn_s_sleep(16);
        }
        // ---- stage into this wave's private LH octants ----
        LH[0][kq0    ][l] = __uint_as_float(v0);
        LH[0][kq0 + 1][l] = __uint_as_float(v1);
        LH[1][kq0    ][l] = __uint_as_float(v2);
        LH[1][kq0 + 1][l] = __uint_as_float(v3);
        LH[2][kq0    ][l] = __uint_as_float(v4);
        LH[2][kq0 + 1][l] = __uint_as_float(v5);
        LH[3][kq0    ][l] = __uint_as_float(v6);
        LH[3][kq0 + 1][l] = __uint_as_float(v7);
        asm volatile("s_waitcnt lgkmcnt(0)" ::: "memory");
        __builtin_amdgcn_sched_barrier(0);
        // ---- dot: 2 cols x 64 k x 4 batches, f32x2 acc (v_pk_fma) ----
        __builtin_amdgcn_s_setprio(1);
        f32x2 a0 = {0.f, 0.f}, a1 = {0.f, 0.f}, a2 = {0.f, 0.f}, a3 = {0.f, 0.f};
#pragma unroll
        for (int j4 = 0; j4 < 16; ++j4) {
          f32x4 h0 = *(const f32x4*)&LH[0][kql][4 * j4];
          f32x4 h1 = *(const f32x4*)&LH[1][kql][4 * j4];
          f32x4 h2 = *(const f32x4*)&LH[2][kql][4 * j4];
          f32x4 h3 = *(const f32x4*)&LH[3][kql][4 * j4];
#pragma unroll
          for (int jj = 0; jj < 4; ++jj) {
            f32x2 wj = W2[4 * j4 + jj];
            a0 += (f32x2){h0[jj], h0[jj]} * wj;
            a1 += (f32x2){h1[jj], h1[jj]} * wj;
            a2 += (f32x2){h2[jj], h2[jj]} * wj;
            a3 += (f32x2){h3[jj], h3[jj]} * wj;
          }
        }
        __builtin_amdgcn_s_setprio(0);
        const int p = t & 1;
        *(f32x2*)&LR[p][kql][0][2 * cp] = a0;
        *(f32x2*)&LR[p][kql][1][2 * cp] = a1;
        *(f32x2*)&LR[p][kql][2][2 * cp] = a2;
        *(f32x2*)&LR[p][kql][3][2 * cp] = a3;
      }
      // ---- pre-gate: xz + bias for batch wv (lanes 0-15), before B2 ----
      float s0 = 0.f, s1 = 0.f, s2 = 0.f, s3 = 0.f;
      if (l < 16) {
        while (__hip_atomic_load(&cXZdone, __ATOMIC_RELAXED,
                                 __HIP_MEMORY_SCOPE_WORKGROUP) < t + 1) {
        }
        asm volatile("" ::: "memory");
        const int ss = t & (RDEPTH - 1);
        s0 = RING[ss][wv][l +  0] + LB[l +  0];
        s1 = RING[ss][wv][l + 16] + LB[l + 16];
        s2 = RING[ss][wv][l + 32] + LB[l + 32];
        s3 = RING[ss][wv][l + 48] + LB[l + 48];
      }
      wavebar<false>(&cCRITbar, epC);  // B2: all LR partials complete
      if (l == 0)
        __hip_atomic_fetch_add(&cCRITdone, 1, __ATOMIC_RELAXED,
                               __HIP_MEMORY_SCOPE_WORKGROUP);
      // ---- gates for batch wv, units w*16 + l (lanes 0-15) ----
      if (l < 16) {
        if (t > 0) {
          const int p = t & 1;
#pragma unroll
          for (int kq = 0; kq < 8; ++kq) {
            s0 += LR[p][kq][wv][l +  0];
            s1 += LR[p][kq][wv][l + 16];
            s2 += LR[p][kq][wv][l + 32];
            s3 += LR[p][kq][wv][l + 48];
          }
        }
        float gi = hsig(s0);
        float gf = hsig(s1);
        float gc = tanh_fast(s2);
        float go = hsig(s3);
        c_state = gf * c_state + gi * gc;
        float h = go * tanh_fast(c_state);
        __hip_atomic_store(
            out + ((size_t)(g * 4 + wv) * TT + t) * UU + w * 16 + l, h,
            __ATOMIC_RELAXED, __HIP_MEMORY_SCOPE_AGENT);
      }
    }
  } else {
    // ---------------- xz pipeline: waves 4-7 (free-running) ----------------
    const int idx = tid & 255;
    const int o   = idx >> 5;
    const int cp  = idx & 31;
    const float* xb0 = x + (size_t)(g * 4 + 0) * TT * DD + o * 64;
    const float* xb1 = x + (size_t)(g * 4 + 1) * TT * DD + o * 64;
    const float* xb2 = x + (size_t)(g * 4 + 2) * TT * DD + o * 64;
    const float* xb3 = x + (size_t)(g * 4 + 3) * TT * DD + o * 64;
    int epX = 0;

    for (int t = 0; t < TT; ++t) {
      const size_t off = (size_t)t * DD;
      f32x2 a0 = {0.f, 0.f}, a1 = {0.f, 0.f}, a2 = {0.f, 0.f}, a3 = {0.f, 0.f};
#pragma unroll
      for (int j4 = 0; j4 < 16; ++j4) {
        f32x4 v0 = *(const f32x4*)(xb0 + off + 4 * j4);
        f32x4 v1 = *(const f32x4*)(xb1 + off + 4 * j4);
        f32x4 v2 = *(const f32x4*)(xb2 + off + 4 * j4);
        f32x4 v3 = *(const f32x4*)(xb3 + off + 4 * j4);
#pragma unroll
        for (int jj = 0; jj < 4; ++jj) {
          f32x2 wj = W2[4 * j4 + jj];
          a0 += (f32x2){v0[jj], v0[jj]} * wj;
          a1 += (f32x2){v1[jj], v1[jj]} * wj;
          a2 += (f32x2){v2[jj], v2[jj]} * wj;
          a3 += (f32x2){v3[jj], v3[jj]} * wj;
        }
      }
      *(f32x2*)&LX[o][0][2 * cp] = a0;
      *(f32x2*)&LX[o][1][2 * cp] = a1;
      *(f32x2*)&LX[o][2][2 * cp] = a2;
      *(f32x2*)&LX[o][3][2 * cp] = a3;
      wavebar<true>(&cXZbar, epX);  // partials visible
      if (t >= RDEPTH) {
        while (__hip_atomic_load(&cCRITdone, __ATOMIC_RELAXED,
                                 __HIP_MEMORY_SCOPE_WORKGROUP) <
               4 * (t - RDEPTH + 1)) {
          __builtin_amdgcn_s_sleep(1);
        }
        asm volatile("" ::: "memory");
      }
      {
        const int b2 = idx >> 6, c3 = idx & 63;
        float ssum = 0.f;
#pragma unroll
        for (int oo = 0; oo < 8; ++oo) ssum += LX[oo][b2][c3];
        RING[t & (RDEPTH - 1)][b2][c3] = ssum;
      }
      wavebar<true>(&cXZbar, epX);  // reduce complete (guards LX overwrite)
      if (idx == 0) {
        asm volatile("s_waitcnt lgkmcnt(0)" ::: "memory");
        __hip_atomic_fetch_add(&cXZdone, 1, __ATOMIC_RELAXED,
                               __HIP_MEMORY_SCOPE_WORKGROUP);
      }
    }
  }
}

extern "C" void kernel_launch(void* const* d_in, const int* in_sizes, int n_in,
                              void* d_out, int out_size, void* d_ws, size_t ws_size,
                              hipStream_t stream) {
  const float* x    = (const float*)d_in[0];
  const float* Wk   = (const float*)d_in[1];
  const float* Wr   = (const float*)d_in[2];
  const float* bias = (const float*)d_in[3];
  float* out = (float*)d_out;

  // Sentinel-fill the h history (graph-capturable async memset).
  hipMemsetAsync(out, 0xFF, (size_t)out_size * sizeof(float), stream);
  lstm_persistent<<<256, 512, 0, stream>>>(x, Wk, Wr, bias, out);
}